// Round 1
// baseline (6722.391 us; speedup 1.0000x reference)
//
#include <hip/hip_runtime.h>
#include <cstdint>
#include <cstddef>

// Problem constants
#define B_  2
#define T_  1024
#define DM  1024
#define H_  16
#define DK_ 64
#define TOPK 128

// ---------- composite key: order by value desc, then by lower index ----------
__device__ __forceinline__ unsigned long long makekey(float v, int s) {
  unsigned u = __float_as_uint(v);
  u = (u & 0x80000000u) ? ~u : (u | 0x80000000u);   // monotone map float -> uint
  return ((unsigned long long)u << 10) | (unsigned)(1023 - s);
}

// ---------- exact top-k threshold via 6x8-bit radix select (blockDim=256) ----
__device__ unsigned long long topk_threshold(float* sc, unsigned* hist,
                                             unsigned* bc, int tid) {
  unsigned long long prefix = 0ull;
  unsigned r = TOPK;
  for (int shift = 40; shift >= 0; shift -= 8) {
    hist[tid] = 0u;
    __syncthreads();
    #pragma unroll
    for (int e = 0; e < 4; ++e) {
      int s = tid * 4 + e;
      unsigned long long key = makekey(sc[s], s);
      if ((key >> (shift + 8)) == prefix)
        atomicAdd(&hist[(unsigned)((key >> shift) & 255ull)], 1u);
    }
    __syncthreads();
    // suffix sum over 256 bins (Hillis-Steele)
    for (int off = 1; off < 256; off <<= 1) {
      unsigned add = (tid + off < 256) ? hist[tid + off] : 0u;
      __syncthreads();
      hist[tid] += add;
      __syncthreads();
    }
    unsigned sfx = hist[tid];
    unsigned nxt = (tid < 255) ? hist[tid + 1] : 0u;
    if (sfx >= r && nxt < r) { bc[0] = (unsigned)tid; bc[1] = nxt; }
    __syncthreads();
    prefix = (prefix << 8) | (unsigned long long)bc[0];
    r -= bc[1];
    __syncthreads();
  }
  return prefix;  // key of the TOPK-th largest element
}

// ---------- fp32 GEMM: C[n][m] = sum_k A[n][k] * Bm[m][k]  (NT) --------------
__global__ __launch_bounds__(256) void gemm_nt_kernel(
    const float* __restrict__ A, const float* __restrict__ Bm,
    float* __restrict__ C, int N, int M, int K) {
  __shared__ float As[16][64];
  __shared__ float Bs[16][64];
  int tid = threadIdx.x;
  int bn = blockIdx.y * 64;
  int bm = blockIdx.x * 64;
  int tx = tid & 15, ty = tid >> 4;
  int lr = tid >> 2;
  int lk = (tid & 3) * 4;
  float acc[4][4] = {{0.f, 0.f, 0.f, 0.f}, {0.f, 0.f, 0.f, 0.f},
                     {0.f, 0.f, 0.f, 0.f}, {0.f, 0.f, 0.f, 0.f}};
  for (int k0 = 0; k0 < K; k0 += 16) {
    float4 a  = *(const float4*)&A [(size_t)(bn + lr) * K + k0 + lk];
    float4 bv = *(const float4*)&Bm[(size_t)(bm + lr) * K + k0 + lk];
    As[lk + 0][lr] = a.x;  As[lk + 1][lr] = a.y;
    As[lk + 2][lr] = a.z;  As[lk + 3][lr] = a.w;
    Bs[lk + 0][lr] = bv.x; Bs[lk + 1][lr] = bv.y;
    Bs[lk + 2][lr] = bv.z; Bs[lk + 3][lr] = bv.w;
    __syncthreads();
    #pragma unroll
    for (int kk = 0; kk < 16; ++kk) {
      float4 av = *(const float4*)&As[kk][ty * 4];
      float4 bw = *(const float4*)&Bs[kk][tx * 4];
      acc[0][0] += av.x * bw.x; acc[0][1] += av.x * bw.y;
      acc[0][2] += av.x * bw.z; acc[0][3] += av.x * bw.w;
      acc[1][0] += av.y * bw.x; acc[1][1] += av.y * bw.y;
      acc[1][2] += av.y * bw.z; acc[1][3] += av.y * bw.w;
      acc[2][0] += av.z * bw.x; acc[2][1] += av.z * bw.y;
      acc[2][2] += av.z * bw.z; acc[2][3] += av.z * bw.w;
      acc[3][0] += av.w * bw.x; acc[3][1] += av.w * bw.y;
      acc[3][2] += av.w * bw.z; acc[3][3] += av.w * bw.w;
    }
    __syncthreads();
  }
  #pragma unroll
  for (int r = 0; r < 4; ++r) {
    float4 o = make_float4(acc[r][0], acc[r][1], acc[r][2], acc[r][3]);
    *(float4*)&C[(size_t)(bn + ty * 4 + r) * M + bm + tx * 4] = o;
  }
}

// ---------- adjacency: row scores + top-128 + softmax -> compact (idx,w) -----
__global__ __launch_bounds__(256) void adj_topk_kernel(
    const float* __restrict__ qf, const float* __restrict__ kf,
    int* __restrict__ aidx, float* __restrict__ aw) {
  __shared__ float sc[1024];
  __shared__ unsigned hist[256];
  __shared__ unsigned bc[2];
  __shared__ float red[256];
  __shared__ float qrow[64];
  int tid = threadIdx.x, bid = blockIdx.x;
  int b = bid >> 14, h = (bid >> 10) & (H_ - 1), t = bid & (T_ - 1);
  const float* kbase = kf + (size_t)b * T_ * DM + h * DK_;
  if (tid < DK_) qrow[tid] = qf[((size_t)(b * T_ + t)) * DM + h * DK_ + tid];
  __syncthreads();
  for (int si = 0; si < 4; ++si) {
    int s = tid + si * 256;
    const float4* kr = (const float4*)(kbase + (size_t)s * DM);
    float acc = 0.f;
    #pragma unroll
    for (int d4 = 0; d4 < 16; ++d4) {
      float4 kv = kr[d4];
      float4 qv = *(const float4*)&qrow[d4 * 4];
      acc += qv.x * kv.x + qv.y * kv.y + qv.z * kv.z + qv.w * kv.w;
    }
    sc[s] = acc * 0.125f;  // 1/sqrt(64)
  }
  __syncthreads();
  unsigned long long thr = topk_threshold(sc, hist, bc, tid);
  // row max (== max of selected)
  float m = -3.402823466e38f;
  #pragma unroll
  for (int e = 0; e < 4; ++e) m = fmaxf(m, sc[tid * 4 + e]);
  red[tid] = m;
  __syncthreads();
  for (int off = 128; off >= 1; off >>= 1) {
    if (tid < off) red[tid] = fmaxf(red[tid], red[tid + off]);
    __syncthreads();
  }
  m = red[0];
  __syncthreads();
  // exp-sum over selected
  float ps = 0.f;
  unsigned cnt = 0;
  #pragma unroll
  for (int e = 0; e < 4; ++e) {
    int s = tid * 4 + e;
    if (makekey(sc[s], s) >= thr) { ps += __expf(sc[s] - m); cnt++; }
  }
  red[tid] = ps;
  __syncthreads();
  for (int off = 128; off >= 1; off >>= 1) {
    if (tid < off) red[tid] += red[tid + off];
    __syncthreads();
  }
  float inv = 1.f / red[0];
  // compact positions via inclusive scan of per-thread counts
  hist[tid] = cnt;
  __syncthreads();
  for (int off = 1; off < 256; off <<= 1) {
    unsigned add = (tid >= off) ? hist[tid - off] : 0u;
    __syncthreads();
    hist[tid] += add;
    __syncthreads();
  }
  unsigned pos = hist[tid] - cnt;
  int base = bid * TOPK;
  #pragma unroll
  for (int e = 0; e < 4; ++e) {
    int s = tid * 4 + e;
    if (makekey(sc[s], s) >= thr) {
      aidx[base + pos] = s;
      aw[base + pos] = __expf(sc[s] - m) * inv;
      pos++;
    }
  }
}

// ---------- one propagation step: D <- (1-lam) D + lam * A D  (r and i) ------
__global__ __launch_bounds__(128) void prop_kernel(
    const float* __restrict__ srcR, const float* __restrict__ srcI,
    float* __restrict__ dstR, float* __restrict__ dstI,
    const int* __restrict__ aidx, const float* __restrict__ aw,
    const float* __restrict__ logit_lam) {
  __shared__ int li[128];
  __shared__ float lw[128];
  int tid = threadIdx.x, bid = blockIdx.x;
  int b = bid >> 14, h = (bid >> 10) & (H_ - 1), t = bid & (T_ - 1);
  li[tid] = aidx[bid * TOPK + tid];
  lw[tid] = aw[bid * TOPK + tid];
  __syncthreads();
  int half = tid >> 6, d = tid & 63;
  const float* src = half ? srcI : srcR;
  float* dst = half ? dstI : dstR;
  size_t colbase = (size_t)b * (T_ * DM) + h * DK_ + d;
  float acc = 0.f;
  #pragma unroll 8
  for (int j = 0; j < 128; ++j)
    acc += lw[j] * src[colbase + (size_t)li[j] * DM];
  float lam = 1.f / (1.f + __expf(-logit_lam[0]));
  size_t own = colbase + (size_t)t * DM;
  dst[own] = (1.f - lam) * src[own] + lam * acc;
}

// ---------- finalize: D += alpha*D0; normalize -> U --------------------------
__global__ __launch_bounds__(64) void finalize_kernel(
    const float* __restrict__ pr, const float* __restrict__ pi,
    const float* __restrict__ d0r, const float* __restrict__ d0i,
    float* __restrict__ ur, float* __restrict__ ui,
    const float* __restrict__ log_alpha) {
  int tid = threadIdx.x, bid = blockIdx.x;
  int b = bid >> 14, h = (bid >> 10) & (H_ - 1), t = bid & (T_ - 1);
  size_t idx = ((size_t)(b * T_ + t)) * DM + h * DK_ + tid;
  float alpha = 1.f / (1.f + __expf(-log_alpha[0]));
  float fr = pr[idx] + alpha * d0r[idx];
  float fi = pi[idx] + alpha * d0i[idx];
  float s = fr * fr + fi * fi;
  #pragma unroll
  for (int off = 32; off >= 1; off >>= 1) s += __shfl_xor(s, off, 64);
  float nrm = fmaxf(sqrtf(s), 1e-6f);
  ur[idx] = fr / nrm;
  ui[idx] = fi / nrm;
}

// ---------- phase sim + top-128 + softmax: dense row out + compact -----------
__global__ __launch_bounds__(256) void phase_topk_kernel(
    const float* __restrict__ ur, const float* __restrict__ ui,
    float* __restrict__ dense, int* __restrict__ pidx, float* __restrict__ pw) {
  __shared__ float sc[1024];
  __shared__ unsigned hist[256];
  __shared__ unsigned bc[2];
  __shared__ float red[256];
  __shared__ float urow[128];
  int tid = threadIdx.x, bid = blockIdx.x;
  int b = bid >> 14, h = (bid >> 10) & (H_ - 1), t = bid & (T_ - 1);
  size_t rowoff = ((size_t)(b * T_ + t)) * DM + h * DK_;
  if (tid < 64) urow[tid] = ur[rowoff + tid];
  else if (tid < 128) urow[tid] = ui[rowoff + (tid - 64)];
  __syncthreads();
  const float* urb = ur + (size_t)b * (T_ * DM) + h * DK_;
  const float* uib = ui + (size_t)b * (T_ * DM) + h * DK_;
  for (int si = 0; si < 4; ++si) {
    int s = tid + si * 256;
    const float4* r4 = (const float4*)(urb + (size_t)s * DM);
    const float4* i4 = (const float4*)(uib + (size_t)s * DM);
    float acc = 0.f;
    #pragma unroll
    for (int d4 = 0; d4 < 16; ++d4) {
      float4 a = r4[d4];
      float4 qv = *(const float4*)&urow[d4 * 4];
      acc += qv.x * a.x + qv.y * a.y + qv.z * a.z + qv.w * a.w;
    }
    #pragma unroll
    for (int d4 = 0; d4 < 16; ++d4) {
      float4 a = i4[d4];
      float4 qv = *(const float4*)&urow[64 + d4 * 4];
      acc += qv.x * a.x + qv.y * a.y + qv.z * a.z + qv.w * a.w;
    }
    sc[s] = acc * 11.3137085f;  // sqrt(2*DK)
  }
  __syncthreads();
  unsigned long long thr = topk_threshold(sc, hist, bc, tid);
  float m = -3.402823466e38f;
  #pragma unroll
  for (int e = 0; e < 4; ++e) m = fmaxf(m, sc[tid * 4 + e]);
  red[tid] = m;
  __syncthreads();
  for (int off = 128; off >= 1; off >>= 1) {
    if (tid < off) red[tid] = fmaxf(red[tid], red[tid + off]);
    __syncthreads();
  }
  m = red[0];
  __syncthreads();
  float ps = 0.f;
  unsigned cnt = 0;
  #pragma unroll
  for (int e = 0; e < 4; ++e) {
    int s = tid * 4 + e;
    if (makekey(sc[s], s) >= thr) { ps += __expf(sc[s] - m); cnt++; }
  }
  red[tid] = ps;
  __syncthreads();
  for (int off = 128; off >= 1; off >>= 1) {
    if (tid < off) red[tid] += red[tid + off];
    __syncthreads();
  }
  float inv = 1.f / red[0];
  hist[tid] = cnt;
  __syncthreads();
  for (int off = 1; off < 256; off <<= 1) {
    unsigned add = (tid >= off) ? hist[tid - off] : 0u;
    __syncthreads();
    hist[tid] += add;
    __syncthreads();
  }
  unsigned pos = hist[tid] - cnt;
  int base = bid * TOPK;
  float w[4];
  #pragma unroll
  for (int e = 0; e < 4; ++e) {
    int s = tid * 4 + e;
    bool sel = makekey(sc[s], s) >= thr;
    float wv = sel ? __expf(sc[s] - m) * inv : 0.f;
    w[e] = wv;
    if (sel) { pidx[base + pos] = s; pw[base + pos] = wv; pos++; }
  }
  *(float4*)&dense[(size_t)bid * 1024 + tid * 4] = make_float4(w[0], w[1], w[2], w[3]);
}

// ---------- weighted V gather: out_head in (B,T,H*DK) flat layout ------------
__global__ __launch_bounds__(64) void attnv_kernel(
    const float* __restrict__ vf, const int* __restrict__ pidx,
    const float* __restrict__ pw, float* __restrict__ outh) {
  __shared__ int li[128];
  __shared__ float lw[128];
  int tid = threadIdx.x, bid = blockIdx.x;
  int b = bid >> 14, h = (bid >> 10) & (H_ - 1), t = bid & (T_ - 1);
  li[tid] = pidx[bid * TOPK + tid];
  li[tid + 64] = pidx[bid * TOPK + tid + 64];
  lw[tid] = pw[bid * TOPK + tid];
  lw[tid + 64] = pw[bid * TOPK + tid + 64];
  __syncthreads();
  size_t colbase = (size_t)b * (T_ * DM) + h * DK_ + tid;
  float acc = 0.f;
  #pragma unroll 8
  for (int j = 0; j < 128; ++j)
    acc += lw[j] * vf[colbase + (size_t)li[j] * DM];
  outh[colbase + (size_t)t * DM] = acc;
}

extern "C" void kernel_launch(void* const* d_in, const int* in_sizes, int n_in,
                              void* d_out, int out_size, void* d_ws, size_t ws_size,
                              hipStream_t stream) {
  (void)in_sizes; (void)n_in; (void)out_size; (void)ws_size;
  const float* x         = (const float*)d_in[0];
  const float* wq        = (const float*)d_in[1];
  const float* wk        = (const float*)d_in[2];
  const float* wre       = (const float*)d_in[3];
  const float* wim       = (const float*)d_in[4];
  const float* wv        = (const float*)d_in[5];
  const float* wo        = (const float*)d_in[6];
  const float* logit_lam = (const float*)d_in[7];
  const float* log_alpha = (const float*)d_in[8];

  float* out   = (float*)d_out;                 // (B,T,DM) = 2,097,152 floats
  float* dense = out + (size_t)B_ * T_ * DM;    // phase_attn (B,H,T,T)

  char* ws = (char*)d_ws;
  const size_t MB8 = (size_t)8 << 20;
  float* q   = (float*)(ws + 0 * MB8);  // later reused as attn_out
  float* k_  = (float*)(ws + 1 * MB8);
  float* d0r = (float*)(ws + 2 * MB8);
  float* d0i = (float*)(ws + 3 * MB8);
  float* v   = (float*)(ws + 4 * MB8);
  float* b1r = (float*)(ws + 5 * MB8);
  float* b1i = (float*)(ws + 6 * MB8);
  float* b2r = (float*)(ws + 7 * MB8);
  float* b2i = (float*)(ws + 8 * MB8);
  float* urp = b1r;  // alias: b1 dead after step 4
  float* uip = b1i;
  int*   aidx = (int*)(ws + 9 * MB8);    // 16 MB (also phase idx)
  float* aw   = (float*)(ws + 11 * MB8); // 16 MB (also phase w)
  // total workspace: 104 MB

  dim3 gb(256);
  dim3 gg(DM / 64, (B_ * T_) / 64);  // (16, 32)
  gemm_nt_kernel<<<gg, gb, 0, stream>>>(x, wq,  q,   B_ * T_, DM, DM);
  gemm_nt_kernel<<<gg, gb, 0, stream>>>(x, wk,  k_,  B_ * T_, DM, DM);
  gemm_nt_kernel<<<gg, gb, 0, stream>>>(x, wre, d0r, B_ * T_, DM, DM);
  gemm_nt_kernel<<<gg, gb, 0, stream>>>(x, wim, d0i, B_ * T_, DM, DM);
  gemm_nt_kernel<<<gg, gb, 0, stream>>>(x, wv,  v,   B_ * T_, DM, DM);

  int rows = B_ * H_ * T_;  // 32768
  adj_topk_kernel<<<rows, 256, 0, stream>>>(q, k_, aidx, aw);

  prop_kernel<<<rows, 128, 0, stream>>>(d0r, d0i, b1r, b1i, aidx, aw, logit_lam);
  prop_kernel<<<rows, 128, 0, stream>>>(b1r, b1i, b2r, b2i, aidx, aw, logit_lam);
  prop_kernel<<<rows, 128, 0, stream>>>(b2r, b2i, b1r, b1i, aidx, aw, logit_lam);
  prop_kernel<<<rows, 128, 0, stream>>>(b1r, b1i, b2r, b2i, aidx, aw, logit_lam);

  finalize_kernel<<<rows, 64, 0, stream>>>(b2r, b2i, d0r, d0i, urp, uip, log_alpha);

  phase_topk_kernel<<<rows, 256, 0, stream>>>(urp, uip, dense, aidx, aw);

  attnv_kernel<<<rows, 64, 0, stream>>>(v, aidx, aw, q /* attn_out */);

  gemm_nt_kernel<<<gg, gb, 0, stream>>>(q, wo, out, B_ * T_, DM, DM);
}